// Round 1
// 1385.582 us; speedup vs baseline: 1.2992x; 1.2992x over previous
//
#include <hip/hip_runtime.h>
#include <hip/hip_bf16.h>

typedef __attribute__((ext_vector_type(8))) short bf16x8;
typedef __attribute__((ext_vector_type(4))) float f32x4;

constexpr int NB = 2048;
constexpr int NE = 30, NN = 8, NAll = 38;
constexpr int BAS = 32, KD = 64, ED = 128, HK = 45, HO = 91, LNUM = 3;

__device__ __forceinline__ unsigned short f2b(float v) {
    __hip_bfloat16 h = __float2bfloat16(v);
    return __builtin_bit_cast(unsigned short, h);
}
__device__ __forceinline__ float ssp(float x) {
    float e = __expf(-fabsf(x));
    return fmaxf(x, 0.f) + __logf(1.f + e) - 0.69314718055994530942f;
}
// XOR-swizzled element index within a pow2-stride row. col need not be aligned.
__device__ __forceinline__ int swzi(int row, int col, int S) {
    int mask = (S >> 3) - 1;
    int blk = ((col >> 3) ^ row) & mask;
    return row * S + (blk << 3) + (col & 7);
}
// bf16 fragment load; col must be 8-aligned.
__device__ __forceinline__ bf16x8 ldfrag(const unsigned short* p, int S, int row, int col) {
    int mask = (S >> 3) - 1;
    int blk = ((col >> 3) ^ row) & mask;
    return *(const bf16x8*)(p + row * S + (blk << 3));
}
// f32x4 swizzled load; col must be 4-aligned and within an 8-block (col%8 in {0,4}).
__device__ __forceinline__ f32x4 ldf4s(const float* p, int S, int row, int col) {
    int mask = (S >> 3) - 1;
    int blk = ((col >> 3) ^ row) & mask;
    return *(const f32x4*)(p + row * S + (blk << 3) + (col & 7));
}
__device__ __forceinline__ bf16x8 cvt8(f32x4 lo, f32x4 hi) {
    bf16x8 r;
    r[0] = (short)f2b(lo[0]); r[1] = (short)f2b(lo[1]);
    r[2] = (short)f2b(lo[2]); r[3] = (short)f2b(lo[3]);
    r[4] = (short)f2b(hi[0]); r[5] = (short)f2b(hi[1]);
    r[6] = (short)f2b(hi[2]); r[7] = (short)f2b(hi[3]);
    return r;
}

__global__ __launch_bounds__(256, 4) void schnet_mfma(
    const float* __restrict__ dists,
    const float* __restrict__ emb_e,
    const float* __restrict__ emb_n,
    const float* __restrict__ kw1, const float* __restrict__ kb1,
    const float* __restrict__ kw2, const float* __restrict__ kb2,
    const float* __restrict__ ew,
    const float* __restrict__ ow1, const float* __restrict__ ob1,
    const float* __restrict__ ow2, const float* __restrict__ ob2,
    float* __restrict__ out)
{
    // 38656 B LDS -> 4 blocks/CU (xs lives in global `out`, not LDS)
    __shared__ __align__(16) unsigned char smem[38656];
    float* zsb  = (float*)smem;              // [38][64] f32 (rows 30..37 = nuc, set once/layer-invariant)
    float* stot = (float*)(smem + 9728);     // [64] column sums of zsb
    unsigned char* U = smem + 9984;          // 28672 B phase-union scratch

    const int b = blockIdx.x;
    const int t = threadIdx.x;
    const int lane = t & 63, wv = t >> 6;
    const int q = lane >> 4, cc = lane & 15;
    const float* db_b = dists + (size_t)b * NE * NAll * BAS;
    float* xsg = out + (size_t)b * NE * ED;  // xs state lives in the output buffer

    const f32x4 zz = {0.f, 0.f, 0.f, 0.f};

    // init xs (= out) from emb_e; nuc rows of zsb (constant across layers)
    for (int o = t; o < NE * ED; o += 256) xsg[o] = emb_e[o];
    for (int o = t; o < NN * KD; o += 256) zsb[NE * KD + o] = emb_n[o];
    __syncthreads();

    for (int l = 0; l < LNUM; ++l) {
        const float* w1g = kw1 + l * BAS * HK;
        const float* b1g = kb1 + l * HK;
        const float* w2g = kw2 + l * HK * KD;
        const float* b2g = kb2 + l * KD;
        const float* weg = ew  + l * ED * KD;
        const float* o1g = ow1 + l * KD * HO;
        const float* g1g = ob1 + l * HO;
        const float* o2g = ow2 + l * ED * 0 + l * HO * ED;  // ow2[l]: [HO][ED]
        const float* g2g = ob2 + l * ED;

        // ================= zs phase: zsb[0:30] = xs @ embed_in_w ================
        {
            unsigned short* wet = (unsigned short*)U;   // Bt [k=64][e=128] bf16
            for (int o = t; o < 64 * 128; o += 256) {
                int k = o & 63, e = o >> 6;             // coalesced over k
                wet[swzi(k, e, 128)] = f2b(weg[e * 64 + k]);
            }
            __syncthreads();
            #pragma unroll
            for (int mt = 0; mt < 2; ++mt) {
                const int row = mt * 16 + cc;
                const bool va = (row < NE);
                f32x4 acc = zz;
                #pragma unroll
                for (int ks = 0; ks < 4; ++ks) {
                    bf16x8 a = {0, 0, 0, 0, 0, 0, 0, 0};
                    if (va) {
                        const float* p = xsg + row * ED + ks * 32 + q * 8;
                        a = cvt8(*(const f32x4*)p, *(const f32x4*)(p + 4));
                    }
                    acc = __builtin_amdgcn_mfma_f32_16x16x32_bf16(
                        a, ldfrag(wet, 128, wv * 16 + cc, ks * 32 + q * 8), acc, 0, 0, 0);
                }
                #pragma unroll
                for (int r = 0; r < 4; ++r) {
                    int rr = mt * 16 + q * 4 + r;
                    if (rr < NE) zsb[rr * 64 + wv * 16 + cc] = acc[r];
                }
            }
            __syncthreads();
        }

        // ============== pair-phase weight staging (once per layer) ==============
        unsigned short* w1t = (unsigned short*)U;            // Bt [h=48][e=32]
        unsigned short* w2t = (unsigned short*)(U + 3072);   // Bt [c=64][h=64pad]
        if (t < 64) {   // column sums of zs for the factored-out b2 term
            float s = 0.f;
            for (int jj = 0; jj < NAll; ++jj) s += zsb[jj * 64 + t];
            stot[t] = s;
        }
        for (int o = t; o < 48 * 32; o += 256) {
            int h = o % 48, e = o / 48;                      // coalesced over h
            float v = (h < HK) ? w1g[e * HK + h] : 0.f;
            w1t[swzi(h, e, 32)] = f2b(v);
        }
        for (int o = t; o < 64 * 64; o += 256) {
            int c2 = o & 63, h = o >> 6;                     // coalesced over c
            float v = (h < HK) ? w2g[h * KD + c2] : 0.f;
            w2t[swzi(c2, h, 64)] = f2b(v);
        }
        __syncthreads();

        // hoist all pair-phase weight fragments into registers
        bf16x8 w1f[3], w2f[4][2];
        float b1v[3];
        #pragma unroll
        for (int nt = 0; nt < 3; ++nt) {
            w1f[nt] = ldfrag(w1t, 32, nt * 16 + cc, q * 8);
            int col = nt * 16 + cc;
            b1v[nt] = (col < HK) ? b1g[col] : 0.f;
        }
        #pragma unroll
        for (int nt = 0; nt < 4; ++nt) {
            w2f[nt][0] = ldfrag(w2t, 64, nt * 16 + cc, q * 8);
            w2f[nt][1] = ldfrag(w2t, 64, nt * 16 + cc, 32 + q * 8);
        }
        __syncthreads();   // all waves done reading w1t/w2t; U becomes per-wave Hb

        // ======== pair phase: per-wave independent j-loop, NO barriers ==========
        unsigned short* Hb = (unsigned short*)(U + wv * 4096);   // private [32][64]
        {   // zero own Hb (pad cols 48..63 must stay 0 for GEMM2 ks=1)
            f32x4* hz = (f32x4*)Hb;
            for (int o = lane; o < 256; o += 64) hz[o] = zz;
        }
        f32x4 mr[2][4];
        #pragma unroll
        for (int mt = 0; mt < 2; ++mt)
            #pragma unroll
            for (int nt = 0; nt < 4; ++nt) mr[mt][nt] = zz;

        for (int j = wv; j < NAll; j += 4) {
            // A-fragments direct from global (8 contiguous floats each)
            const float* dp0 = db_b + (cc * NAll + j) * BAS + q * 8;
            bf16x8 fa0 = cvt8(*(const f32x4*)dp0, *(const f32x4*)(dp0 + 4));
            bf16x8 fa1 = {0, 0, 0, 0, 0, 0, 0, 0};
            if (cc < NE - 16) {   // rows 30,31 padded with zero (and avoid OOB)
                const float* dp1 = dp0 + 16 * NAll * BAS;
                fa1 = cvt8(*(const f32x4*)dp1, *(const f32x4*)(dp1 + 4));
            }
            // GEMM1 [32x32]@[32x48] + ssp -> private Hb
            #pragma unroll
            for (int nt = 0; nt < 3; ++nt) {
                f32x4 h0 = __builtin_amdgcn_mfma_f32_16x16x32_bf16(fa0, w1f[nt], zz, 0, 0, 0);
                f32x4 h1 = __builtin_amdgcn_mfma_f32_16x16x32_bf16(fa1, w1f[nt], zz, 0, 0, 0);
                int col = nt * 16 + cc;
                float bb = b1v[nt];
                #pragma unroll
                for (int r = 0; r < 4; ++r) {
                    Hb[swzi(q * 4 + r, col, 64)]      = f2b(ssp(h0[r] + bb));
                    Hb[swzi(16 + q * 4 + r, col, 64)] = f2b(ssp(h1[r] + bb));
                }
            }
            // GEMM2 [32x48]@[48x64]; epilogue: mr += W * zs[j]  (b2 factored out)
            float zv[4];
            #pragma unroll
            for (int nt = 0; nt < 4; ++nt) zv[nt] = zsb[j * 64 + nt * 16 + cc];
            #pragma unroll
            for (int mt = 0; mt < 2; ++mt) {
                bf16x8 afA = ldfrag(Hb, 64, mt * 16 + cc, q * 8);
                bf16x8 afB = ldfrag(Hb, 64, mt * 16 + cc, 32 + q * 8);
                #pragma unroll
                for (int nt = 0; nt < 4; ++nt) {
                    f32x4 acc = __builtin_amdgcn_mfma_f32_16x16x32_bf16(afA, w2f[nt][0], zz, 0, 0, 0);
                    acc = __builtin_amdgcn_mfma_f32_16x16x32_bf16(afB, w2f[nt][1], acc, 0, 0, 0);
                    #pragma unroll
                    for (int r = 0; r < 4; ++r) {
                        int ii = mt * 16 + q * 4 + r;
                        if (ii < NE && j != ii) mr[mt][nt][r] += acc[r] * zv[nt];
                    }
                }
            }
        }
        __syncthreads();   // all waves done with private Hb; U becomes msg buffers

        // =============== cross-wave msg reduction (fp32, in LDS) ================
        float* msgf0 = (float*)U;              // [32][64] swizzled
        float* msgf1 = (float*)(U + 8192);
        if (wv < 2) {
            float* dst = wv ? msgf1 : msgf0;
            #pragma unroll
            for (int mt = 0; mt < 2; ++mt)
                #pragma unroll
                for (int nt = 0; nt < 4; ++nt) {
                    int col = nt * 16 + cc;
                    #pragma unroll
                    for (int r = 0; r < 4; ++r) {
                        int i = mt * 16 + q * 4 + r;
                        float v = mr[mt][nt][r];
                        if (wv == 0 && i < NE)   // apply factored b2 term once
                            v += b2g[col] * (stot[col] - zsb[i * 64 + col]);
                        dst[swzi(i, col, 64)] = v;
                    }
                }
        }
        __syncthreads();
        if (wv >= 2) {
            float* dst = (wv == 3) ? msgf1 : msgf0;
            #pragma unroll
            for (int mt = 0; mt < 2; ++mt)
                #pragma unroll
                for (int nt = 0; nt < 4; ++nt) {
                    int col = nt * 16 + cc;
                    #pragma unroll
                    for (int r = 0; r < 4; ++r)
                        dst[swzi(mt * 16 + q * 4 + r, col, 64)] += mr[mt][nt][r];
                }
        }
        __syncthreads();
        for (int o = t; o < 2048; o += 256) msgf0[o] += msgf1[o];
        __syncthreads();

        // ================= out phase: xs += ssp(msg@o1+b1o)@o2+b2o ==============
        {
            unsigned short* o1t = (unsigned short*)(U + 8192);    // Bt [h=96][m=64]
            unsigned short* hob = (unsigned short*)(U + 20480);   // A  [32][128pad]
            for (int o = t; o < 96 * 64; o += 256) {
                int h = o % 96, m = o / 96;                       // coalesced over h
                float v = (h < HO) ? o1g[m * HO + h] : 0.f;
                o1t[swzi(h, m, 64)] = f2b(v);
            }
            __syncthreads();
            // GEMM o1 [32x64]@[64x96] + ssp -> hob (A from fp32 msgf0, cvt in reg)
            {
                const int mt = wv & 1;
                bf16x8 afo[2];
                #pragma unroll
                for (int ks = 0; ks < 2; ++ks) {
                    f32x4 p0 = ldf4s(msgf0, 64, mt * 16 + cc, ks * 32 + q * 8);
                    f32x4 p1 = ldf4s(msgf0, 64, mt * 16 + cc, ks * 32 + q * 8 + 4);
                    afo[ks] = cvt8(p0, p1);
                }
                #pragma unroll
                for (int s = 0; s < 3; ++s) {
                    int nt = (wv >> 1) + 2 * s;
                    f32x4 acc = __builtin_amdgcn_mfma_f32_16x16x32_bf16(
                        afo[0], ldfrag(o1t, 64, nt * 16 + cc, q * 8), zz, 0, 0, 0);
                    acc = __builtin_amdgcn_mfma_f32_16x16x32_bf16(
                        afo[1], ldfrag(o1t, 64, nt * 16 + cc, 32 + q * 8), acc, 0, 0, 0);
                    int col = nt * 16 + cc;
                    float g1v = (col < HO) ? g1g[col] : 0.f;
                    #pragma unroll
                    for (int r = 0; r < 4; ++r)   // cols 91..95 store ssp(0)=0 pad
                        hob[swzi(mt * 16 + q * 4 + r, col, 128)] = f2b(ssp(acc[r] + g1v));
                }
            }
            __syncthreads();
            // GEMM o2 [32x96]@[96x64] per ED half; += into global xs
            unsigned short* o2t = (unsigned short*)U;             // Bt [e=64][h=128pad]
            #pragma unroll
            for (int ph = 0; ph < 2; ++ph) {
                for (int o = t; o < 8192; o += 256) {
                    int e = o & 63, h = o >> 6;                   // coalesced over e
                    float v = (h < HO) ? o2g[h * ED + ph * 64 + e] : 0.f;
                    o2t[swzi(e, h, 128)] = f2b(v);
                }
                __syncthreads();
                float g2v = g2g[ph * 64 + wv * 16 + cc];
                #pragma unroll
                for (int mt = 0; mt < 2; ++mt) {
                    f32x4 acc = zz;
                    #pragma unroll
                    for (int ks = 0; ks < 3; ++ks)
                        acc = __builtin_amdgcn_mfma_f32_16x16x32_bf16(
                            ldfrag(hob, 128, mt * 16 + cc, ks * 32 + q * 8),
                            ldfrag(o2t, 128, wv * 16 + cc, ks * 32 + q * 8), acc, 0, 0, 0);
                    #pragma unroll
                    for (int r = 0; r < 4; ++r) {
                        int i = mt * 16 + q * 4 + r;
                        if (i < NE) xsg[i * ED + ph * 64 + wv * 16 + cc] += acc[r] + g2v;
                    }
                }
                __syncthreads();   // before restaging o2t / next layer's zs reads
            }
        }
    }
    // xs state was accumulated directly in `out` — nothing left to write.
}

extern "C" void kernel_launch(void* const* d_in, const int* in_sizes, int n_in,
                              void* d_out, int out_size, void* d_ws, size_t ws_size,
                              hipStream_t stream) {
    const float* dists = (const float*)d_in[0];
    const float* emb_e = (const float*)d_in[1];
    const float* emb_n = (const float*)d_in[2];
    const float* kw1   = (const float*)d_in[3];
    const float* kb1   = (const float*)d_in[4];
    const float* kw2   = (const float*)d_in[5];
    const float* kb2   = (const float*)d_in[6];
    const float* ew    = (const float*)d_in[7];
    const float* ow1   = (const float*)d_in[8];
    const float* ob1   = (const float*)d_in[9];
    const float* ow2   = (const float*)d_in[10];
    const float* ob2   = (const float*)d_in[11];
    float* out = (float*)d_out;

    schnet_mfma<<<NB, 256, 0, stream>>>(dists, emb_e, emb_n, kw1, kb1, kw2, kb2,
                                        ew, ow1, ob1, ow2, ob2, out);
}